// Round 12
// baseline (232.656 us; speedup 1.0000x reference)
//
#include <hip/hip_runtime.h>

#define NN   4096
#define KNBR 8
#define DF   240
#define NSUB 16   // candidate sub-ranges (waves) per kNN block
#define QPB  64   // queries per kNN block

// LDS layout (bytes). Phase A (kNN): cnd/pd/pi/thr/nbrL. Phase B (msg):
// WfL/sevL/snbL/accL — all dead-alias phase-A regions except nbrL.
#define OFF_PD   49152   // float [16][64][9]  = 36864
#define OFF_PI   86016   // ushort[16][64][9]  = 18432
#define OFF_THR  104448  // float [64]         = 256
#define OFF_NBR  104704  // int   [64][8]      = 2048 (merge -> stage handoff)
#define OFF_WF   0       // float [5120]       = 20480
#define OFF_SEV  20480   // float [64][8][3]   = 6144
#define OFF_SNB  26624   // int   [64][8]      = 2048
#define OFF_ACC  28672   // float [16][432]    = 27648
#define SMEM_SZ  106752

// 9-deep distance-only sorted insert (for the 9th-smallest threshold).
__device__ __forceinline__ void insD9(float v, float t[9]) {
#pragma unroll
  for (int k = 8; k >= 1; k--)
    t[k] = __builtin_amdgcn_fmed3f(t[k - 1], t[k], v);
  t[0] = fminf(t[0], v);
}

// (distance,index) sorted-top-8 insert — proven formulation:
__device__ __forceinline__ void insertDI(float d2, int j, float bd[KNBR],
                                         int bi[KNBR]) {
#pragma unroll
  for (int k = KNBR - 1; k >= 1; k--) {
    bool mk  = d2 < bd[k];
    bool mk1 = d2 < bd[k - 1];
    bd[k] = mk ? (mk1 ? bd[k - 1] : d2) : bd[k];
    bi[k] = mk ? (mk1 ? bi[k - 1] : j) : bi[k];
  }
  bool m0 = d2 < bd[0];
  bd[0] = m0 ? d2 : bd[0];
  bi[0] = m0 ? j : bi[0];
}

// ---- phase-B prefetch chunk: 4 neighbor rows in registers. Arrays indexed
// ---- only by constant unrolled indices (rule #20). Two instances (cA_/cB_)
// ---- give a 2-deep pipeline without dynamic selection. R9 proved this
// ---- spills at a 64-VGPR cap; R11 lifts the cap to 128 via (1024,1).
#define CH_DECL(P)                                                  \
  const float* P##fr[4];                                            \
  float P##xv[4], P##av0[4], P##av1[4], P##av2[4],                  \
        P##bv0[4], P##bv1[4], P##bv2[4], P##bv3[4], P##bv4[4];

#define CH_LOAD(P, NL, H)                                           \
  do {                                                              \
    _Pragma("unroll") for (int i = 0; i < 4; i++) {                 \
      P##fr[i] =                                                    \
          feats + (size_t)snbL[(NL) * KNBR + 4 * (H) + i] * DF;     \
      P##xv[i] = P##fr[i][u];                                       \
    }                                                               \
    if (u < 32) {                                                   \
      _Pragma("unroll") for (int i = 0; i < 4; i++) {               \
        P##av0[i] = P##fr[i][64 + 3 * u];                           \
        P##av1[i] = P##fr[i][65 + 3 * u];                           \
        P##av2[i] = P##fr[i][66 + 3 * u];                           \
      }                                                             \
      if (u < 16) {                                                 \
        _Pragma("unroll") for (int i = 0; i < 4; i++) {             \
          P##bv0[i] = P##fr[i][160 + 5 * u];                        \
          P##bv1[i] = P##fr[i][161 + 5 * u];                        \
          P##bv2[i] = P##fr[i][162 + 5 * u];                        \
          P##bv3[i] = P##fr[i][163 + 5 * u];                        \
          P##bv4[i] = P##fr[i][164 + 5 * u];                        \
        }                                                           \
      }                                                             \
    }                                                               \
  } while (0)

#define CH_CONS(P, NL, H)                                           \
  do {                                                              \
    _Pragma("unroll") for (int i = 0; i < 4; i++) {                 \
      const int e = 4 * (H) + i;                                    \
      float X = sevL[((NL) * KNBR + e) * 3 + 0];                    \
      float Y = sevL[((NL) * KNBR + e) * 3 + 1];                    \
      float Z = sevL[((NL) * KNBR + e) * 3 + 2];                    \
      float sxv = S_ * X, syv = S_ * Y, szv = S_ * Z;               \
      float txv = T_ * X, tyv = T_ * Y, t2z = 2.f * T_ * Z;         \
      z0x += P##xv[i] * X;                                          \
      z0y += P##xv[i] * Y;                                          \
      z0z += P##xv[i] * Z;                                          \
      if (u < 32) {                                                 \
        s1 += P##av0[i] * X + P##av1[i] * Y + P##av2[i] * Z;        \
        p0 += P##av0[i] * syv + P##av1[i] * sxv;                    \
        p1 += P##av0[i] * szv + P##av2[i] * sxv;                    \
        p2 += P##av1[i] * szv + P##av2[i] * syv;                    \
        p3 += P##av0[i] * sxv - P##av1[i] * syv;                    \
        p4 += P##av2[i] * t2z - P##av0[i] * txv - P##av1[i] * tyv;  \
        if (u < 16) {                                               \
          q0 += P##bv0[i] * syv + P##bv1[i] * szv +                 \
                P##bv3[i] * sxv - P##bv4[i] * txv;                  \
          q1 += P##bv0[i] * sxv + P##bv2[i] * szv -                 \
                P##bv3[i] * syv - P##bv4[i] * tyv;                  \
          q2 += P##bv1[i] * sxv + P##bv2[i] * syv + P##bv4[i] * t2z;\
        }                                                           \
      }                                                             \
    }                                                               \
  } while (0)

// ---------------------------------------------------------------------------
// ONE kernel, grid 256 x 1024. BATCH-MAJOR block mapping (b = blk & 3):
// blockIdx round-robins XCDs, so each XCD serves ~one batch whose ~3.9 MB
// feats slab fits its 4 MB L2 (R10 counters: FETCH 110 -> 30 MB).
//
// R11: __launch_bounds__(1024, 1). The 107 KB LDS caps the CU at ONE block
// (= 4 waves/EU), for which the true VGPR budget is 128. Without the
// explicit min-waves=1, the allocator's heuristic pinned VGPR=64 and spilled
// ~13 MB each way every dispatch (R8-R10: WRITE_SIZE 29 MB vs 15.7 MB
// output; matching spill reloads inside FETCH). Lifting the cap also
// un-starves the R9 2-deep phase-B pipeline, reinstated below.
//
// Phase A (kNN, verified R8 structure): A1 stage 4096 cands to LDS ->
// A2 per-sub top-2 (no self mask) -> A3 thr = 9th-smallest of 32 (self-0
// present exactly once => equals 8th of real subset => valid bound; exact)
// -> A4 group-guarded exact collect (self masked) -> A5 merge (ascending
// sub = ascending j, strict-< == reference stable tie-break) -> nbrL.
//
// Phase B: B1 weight fusion into LDS + sev/snb staging. B2 per wave, 4 nodes,
// SOFTWARE-PIPELINED: issue ch(n,1) | consume ch(n,0) | issue ch(n+1,0) |
// consume ch(n,1) | write moments | epilogue(n) overlaps ch(n+1,0)'s HBM/L2
// latency (T14). lgkmcnt fences order same-wave LDS RAW/WAR and do NOT
// drain vmcnt, so the prefetch stays in flight under the epilogue.
// ---------------------------------------------------------------------------
__global__ __launch_bounds__(1024, 1) void fused_all(
    const float* __restrict__ feats, const float* __restrict__ coords,
    const float* __restrict__ W1, const float* __restrict__ W2,
    const float* __restrict__ W3, const float* __restrict__ W4,
    const float* __restrict__ L0, const float* __restrict__ L1,
    const float* __restrict__ L2, float* __restrict__ out) {
  __shared__ __align__(16) char smem[SMEM_SZ];

  const int blk = blockIdx.x;
  const int b = blk & 3;                      // batch-major: XCD ~= batch
  const int chunk = blk >> 2;
  const int qi  = threadIdx.x & 63;           // query lane
  const int sub = threadIdx.x >> 6;           // 0..15
  const int iq  = chunk * 64 + qi;
  const float* cb = coords + (size_t)b * NN * 3;
  const float4* cb4 = (const float4*)cb;

  float4* cnd = (float4*)smem;
  float* pdB = (float*)(smem + OFF_PD);            // (s*64+q)*9 + k
  unsigned short* piB = (unsigned short*)(smem + OFF_PI);
  float* thrS = (float*)(smem + OFF_THR);
  int* nbrL = (int*)(smem + OFF_NBR);

  {  // A1: stage all 4096 candidates: 3072 float4, 3 per thread, coalesced
    int t = threadIdx.x;
    cnd[t]        = cb4[t];
    cnd[1024 + t] = cb4[1024 + t];
    cnd[2048 + t] = cb4[2048 + t];
  }
  const float qx = cb[iq * 3 + 0], qy = cb[iq * 3 + 1], qz = cb[iq * 3 + 2];
  __syncthreads();

  const int j0 = sub * 256;

  // ---- A2: top-2 distances over [j0, j0+256) (no self mask; see A3)
  float t0v = 3.0e38f, t1v = 3.0e38f;
#pragma unroll 8
  for (int g = 0; g < 64; ++g) {
    int f = 3 * (sub * 64 + g);
    float4 f0 = cnd[f + 0];                   // wave-uniform -> broadcast
    float4 f1 = cnd[f + 1];
    float4 f2 = cnd[f + 2];
    float xs[4] = {f0.x, f0.w, f1.z, f2.y};
    float ys[4] = {f0.y, f1.x, f1.w, f2.z};
    float zs[4] = {f0.z, f1.y, f2.x, f2.w};
#pragma unroll
    for (int c = 0; c < 4; ++c) {
      float dx = xs[c] - qx, dy = ys[c] - qy, dz = zs[c] - qz;
      float d2 = dx * dx + dy * dy + dz * dz;
      t1v = __builtin_amdgcn_fmed3f(t0v, t1v, d2);
      t0v = fminf(t0v, d2);
    }
  }
  pdB[(sub * 64 + qi) * 9 + 0] = t0v;
  pdB[(sub * 64 + qi) * 9 + 1] = t1v;
  __syncthreads();

  // ---- A3: thr = 9th smallest of 32 values (self-0 present exactly once)
  if (threadIdx.x < 64) {
    const int q = threadIdx.x;
    float md[9];
#pragma unroll
    for (int k = 0; k < 9; k++) md[k] = 3.0e38f;
    for (int s = 0; s < NSUB; s++) {
      insD9(pdB[(s * 64 + q) * 9 + 0], md);
      insD9(pdB[(s * 64 + q) * 9 + 1], md);
    }
    thrS[q] = md[8];
  }
  __syncthreads();

  // ---- A4: group-guarded exact collect (self masked here)
  const float tq = thrS[qi];
  float bd[KNBR];
  int bi[KNBR];
#pragma unroll
  for (int k = 0; k < KNBR; k++) { bd[k] = 3.0e38f; bi[k] = 0; }
#pragma unroll 2
  for (int g = 0; g < 64; ++g) {
    int base = j0 + 4 * g;
    int f = 3 * (sub * 64 + g);
    float4 f0 = cnd[f + 0];
    float4 f1 = cnd[f + 1];
    float4 f2 = cnd[f + 2];
    float xs[4] = {f0.x, f0.w, f1.z, f2.y};
    float ys[4] = {f0.y, f1.x, f1.w, f2.z};
    float zs[4] = {f0.z, f1.y, f2.x, f2.w};
    float d2s[4];
#pragma unroll
    for (int c = 0; c < 4; ++c) {
      float dx = xs[c] - qx, dy = ys[c] - qy, dz = zs[c] - qz;
      float d2 = dx * dx + dy * dy + dz * dz;
      d2s[c] = (base + c == iq) ? 3.0e38f : d2;
    }
    float m4 = fminf(fminf(d2s[0], d2s[1]), fminf(d2s[2], d2s[3]));
    if (m4 <= tq) {                           // rare
#pragma unroll
      for (int c = 0; c < 4; ++c)
        if (d2s[c] <= tq) insertDI(d2s[c], base + c, bd, bi);
    }
  }
#pragma unroll
  for (int k = 0; k < KNBR; k++) {
    pdB[(sub * 64 + qi) * 9 + k] = bd[k];
    piB[(sub * 64 + qi) * 9 + k] = (unsigned short)bi[k];
  }
  __syncthreads();

  // ---- A5: final merge -> nbrL (batch-local ids), LDS only
  if (threadIdx.x < 64) {
    const int q = threadIdx.x;
    float md[KNBR];
    int mi[KNBR];
#pragma unroll
    for (int k = 0; k < KNBR; k++) { md[k] = 3.0e38f; mi[k] = 0; }
    for (int s = 0; s < NSUB; s++) {
#pragma unroll
      for (int k = 0; k < KNBR; k++) {
        float vd = pdB[(s * 64 + q) * 9 + k];
        if (vd < md[KNBR - 1]) insertDI(vd, (int)piB[(s * 64 + q) * 9 + k],
                                        md, mi);
      }
    }
#pragma unroll
    for (int k = 0; k < KNBR; k++) nbrL[q * KNBR + k] = mi[k];
  }
  __syncthreads();

  // ================= Phase B =================
  float* WfL  = (float*)(smem + OFF_WF);
  float* sevL = (float*)(smem + OFF_SEV);
  int*   snbL = (int*)(smem + OFF_SNB);
  float* accL = (float*)(smem + OFF_ACC);

  // ---- B1a: per-block weight fusion into LDS (5 entries per thread)
  {
    const float sA = 0.012757759076995719f;  // sqrt(1/96)/8
    const float sB = 0.019764235376052370f;  // 1/sqrt(80*32)
    const float sC = 0.034232659844072875f;  // sqrt(3)/sqrt(80*32)
    const float sD = 0.098821176880261850f;  // sqrt(5/32)/4
#pragma unroll
    for (int i = 0; i < 5; i++) {
      int idx = threadIdx.x + 1024 * i;      // [0,5120)
      if (idx < 2048) {                      // WA: W2(32x64) @ L0(64x64)
        int u2 = idx >> 6, c = idx & 63;
        float a = 0.f;
#pragma unroll 8
        for (int m = 0; m < 64; m++) a += W2[u2 * 64 + m] * L0[m * 64 + c];
        WfL[idx] = sA * a;
      } else if (idx < 4096) {               // WB: W1(64x32) @ L1(32x32)
        int t = idx - 2048;
        int u2 = t >> 5, c = t & 31;
        float a = 0.f;
#pragma unroll 8
        for (int m = 0; m < 32; m++) a += W1[u2 * 32 + m] * L1[m * 32 + c];
        WfL[idx] = sB * a;
      } else if (idx < 4608) {               // WC: W4(16x32) @ L1(32x32)
        int t = idx - 4096;
        int u2 = t >> 5, c = t & 31;
        float a = 0.f;
#pragma unroll 8
        for (int m = 0; m < 32; m++) a += W4[u2 * 32 + m] * L1[m * 32 + c];
        WfL[idx] = sC * a;
      } else {                               // WD: W3(32x16) @ L2(16x16)
        int t = idx - 4608;
        int u2 = t >> 4, c = t & 15;
        float a = 0.f;
#pragma unroll 8
        for (int m = 0; m < 16; m++) a += W3[u2 * 16 + m] * L2[m * 16 + c];
        WfL[idx] = sD * a;
      }
    }
  }
  // ---- B1b: sev/snb staging (64 nodes x 8 nbrs, coords from global/L2)
  if (threadIdx.x < 512) {
    int t = threadIdx.x;
    int nl = t >> 3, e = t & 7;
    int jj = nbrL[nl * KNBR + e];            // batch-local
    int iqn = chunk * 64 + nl;
    snbL[t] = b * NN + jj;                   // global id for feats
    sevL[3 * t + 0] = cb[jj * 3 + 0] - cb[iqn * 3 + 0];
    sevL[3 * t + 1] = cb[jj * 3 + 1] - cb[iqn * 3 + 1];
    sevL[3 * t + 2] = cb[jj * 3 + 2] - cb[iqn * 3 + 2];
  }
  __syncthreads();

  // ---- B2: per wave, 4 nodes, 2-chunk software pipeline
  const float S_ = 0.31622776601683794f;  // 1/sqrt(10)
  const float T_ = 0.18257418583505536f;  // 1/sqrt(30)
  const int w = threadIdx.x >> 6;
  const int u = threadIdx.x & 63;
  float* A = accL + w * 432;  // S1[32]@0 | Z0[64][3]@32 | P[32][5]@224 | Q[16][3]@384

  CH_DECL(cA_)
  CH_DECL(cB_)
  CH_LOAD(cA_, w * 4, 0);                    // prologue: first chunk in flight

  for (int i2 = 0; i2 < 4; i2++) {
    const int nl = w * 4 + i2;
    const int node = b * NN + chunk * 64 + nl;   // global node id

    float z0x = 0.f, z0y = 0.f, z0z = 0.f;
    float s1 = 0.f, p0 = 0.f, p1 = 0.f, p2 = 0.f, p3 = 0.f, p4 = 0.f;
    float q0 = 0.f, q1 = 0.f, q2 = 0.f;

    CH_LOAD(cB_, nl, 1);                     // issue 2nd chunk of this node
    CH_CONS(cA_, nl, 0);                     // consume 1st (issued earlier)
    if (i2 < 3) CH_LOAD(cA_, nl + 1, 0);     // issue next node's 1st chunk
    CH_CONS(cB_, nl, 1);                     // consume 2nd

    A[32 + 3 * u + 0] = z0x;
    A[32 + 3 * u + 1] = z0y;
    A[32 + 3 * u + 2] = z0z;
    if (u < 32) {
      A[u] = s1;
      float* pp = A + 224 + 5 * u;
      pp[0] = p0; pp[1] = p1; pp[2] = p2; pp[3] = p3; pp[4] = p4;
    }
    if (u < 16) {
      float* qq = A + 384 + 3 * u;
      qq[0] = q0; qq[1] = q1; qq[2] = q2;
    }
    // same-wave LDS RAW: drain DS queue (does not drain vmcnt -> the
    // cA_ prefetch for node nl+1 stays in flight under the epilogue).
    asm volatile("s_waitcnt lgkmcnt(0)" ::: "memory");

    const float* WA = WfL;          // 32x64
    const float* WB = WfL + 2048;   // 64x32
    const float* WC = WfL + 4096;   // 16x32
    const float* WD = WfL + 4608;   // 32x16
    float* orow = out + (size_t)node * DF;

    {  // y0[u] = sum_m S1[m] * WA[m][u]   (coalesced across lanes)
      float a = 0.f;
#pragma unroll
      for (int m = 0; m < 32; m++) a += A[m] * WA[m * 64 + u];
      orow[u] = a;
    }
#pragma unroll
    for (int m0 = 0; m0 < 96; m0 += 64) {   // y1 flat [w1*3+k]
      int m = m0 + u;
      if (m < 96) {
        int w1 = m / 3, k = m - w1 * 3;
        float a = 0.f;
#pragma unroll
        for (int t = 0; t < 64; t++) a += A[32 + 3 * t + k] * WB[t * 32 + w1];
#pragma unroll
        for (int t = 0; t < 16; t++) a += A[384 + 3 * t + k] * WC[t * 32 + w1];
        orow[64 + m] = a;
      }
    }
#pragma unroll
    for (int m0 = 0; m0 < 80; m0 += 64) {   // y2 flat [w2*5+k]
      int m = m0 + u;
      if (m < 80) {
        int w2 = m / 5, k = m - w2 * 5;
        float a = 0.f;
#pragma unroll
        for (int t = 0; t < 32; t++) a += A[224 + 5 * t + k] * WD[t * 16 + w2];
        orow[160 + m] = a;
      }
    }
    // WAR: this iteration's A reads must not reorder after next iteration's
    // A writes (compiler fence; DS unit is in-order per wave).
    asm volatile("s_waitcnt lgkmcnt(0)" ::: "memory");
  }
}

// ---------------------------------------------------------------------------
extern "C" void kernel_launch(void* const* d_in, const int* in_sizes, int n_in,
                              void* d_out, int out_size, void* d_ws,
                              size_t ws_size, hipStream_t stream) {
  const float* feats  = (const float*)d_in[0];
  const float* coords = (const float*)d_in[1];
  const float* W1 = (const float*)d_in[2];
  const float* W2 = (const float*)d_in[3];
  const float* W3 = (const float*)d_in[4];
  const float* W4 = (const float*)d_in[5];
  const float* L0 = (const float*)d_in[6];
  const float* L1 = (const float*)d_in[7];
  const float* L2 = (const float*)d_in[8];
  float* out = (float*)d_out;
  (void)d_ws; (void)ws_size;   // workspace not needed

  fused_all<<<256, 1024, 0, stream>>>(feats, coords, W1, W2, W3, W4, L0, L1,
                                      L2, out);
}

// Round 13
// 185.154 us; speedup vs baseline: 1.2566x; 1.2566x over previous
//
#include <hip/hip_runtime.h>

#define NN   4096
#define KNBR 8
#define DF   240
#define NSUB 16   // candidate sub-ranges (waves) per kNN block
#define QPB  64   // queries per kNN block

// 9-deep distance-only sorted insert (for the 9th-smallest threshold).
__device__ __forceinline__ void insD9(float v, float t[9]) {
#pragma unroll
  for (int k = 8; k >= 1; k--)
    t[k] = __builtin_amdgcn_fmed3f(t[k - 1], t[k], v);
  t[0] = fminf(t[0], v);
}

// (distance,index) sorted-top-8 insert — proven formulation:
__device__ __forceinline__ void insertDI(float d2, int j, float bd[KNBR],
                                         int bi[KNBR]) {
#pragma unroll
  for (int k = KNBR - 1; k >= 1; k--) {
    bool mk  = d2 < bd[k];
    bool mk1 = d2 < bd[k - 1];
    bd[k] = mk ? (mk1 ? bd[k - 1] : d2) : bd[k];
    bi[k] = mk ? (mk1 ? bi[k - 1] : j) : bi[k];
  }
  bool m0 = d2 < bd[0];
  bd[0] = m0 ? d2 : bd[0];
  bi[0] = m0 ? j : bi[0];
}

// ---------------------------------------------------------------------------
// Kernel 1: full kNN (R8-verified phase-A structure) ⊕ weight fusion.
// R13 post-mortem of R9-R12: hipcc pins 1024-thread kernels at 64 VGPR no
// matter what launch_bounds says -> register-hungry phase-B can NEVER live
// in this kernel without spilling (WRITE_SIZE 148 MB). So the msg phase goes
// back to its own 256-thread kernel (cap 128, honored — R4 measured VGPR 56
// spill-free), and this kernel keeps only the kNN (VGPR 52 in R7, no spill).
//
//   blocks [0,256): block = (batch b=blk>>6, 64-query chunk).
//     A1: stage all 4096 cands to LDS (raw float4 image, coalesced).
//     A2: per-sub top-2 distances, NO self mask (8 VALU/cand), unroll 8.
//     A3: thr = 9TH smallest of the 32 values. Self-distance 0 is present
//         exactly once (random coords: no exact dup) and is the minimum, so
//         9th-of-(S u {0}) = 8th-of-S, S subset of real distances => thr >=
//         true 8th. Exact superset admit; refcheck'd through R8-R12.
//     A4: group-guarded exact collect (self masked; min-of-4 guard).
//     A5: merge (ascending sub = ascending j, strict-< == reference stable
//         top_k tie-break) -> nbr (GLOBAL node ids).
//   blocks [256,261): weight fusion (5120 outputs, non-transposed — the
//     msg epilogue reads W[m*stride+u], coalesced ACROSS lanes; R5 proved
//     the per-lane-row transposed form is the uncoalesced regression):
//     WA = sA*(W2@L0) 32x64 @0    | WB = sB*(W1@L1) 64x32 @2048
//     WC = sC*(W4@L1) 16x32 @4096 | WD = sD*(W3@L2) 32x16 @4608
// ---------------------------------------------------------------------------
__global__ __launch_bounds__(1024) void knn_all(
    const float* __restrict__ coords,
    const float* __restrict__ W1, const float* __restrict__ W2,
    const float* __restrict__ W3, const float* __restrict__ W4,
    const float* __restrict__ L0, const float* __restrict__ L1,
    const float* __restrict__ L2, float* __restrict__ Wf,
    int* __restrict__ nbr) {
  if (blockIdx.x >= 256) {             // -------- weight-fusion blocks
    const float sA = 0.012757759076995719f;  // sqrt(1/96)/8
    const float sB = 0.019764235376052370f;  // 1/sqrt(80*32)
    const float sC = 0.034232659844072875f;  // sqrt(3)/sqrt(80*32)
    const float sD = 0.098821176880261850f;  // sqrt(5/32)/4
    int idx = (blockIdx.x - 256) * 1024 + threadIdx.x;  // [0,5120)
    if (idx < 2048) {                       // WA: W2(32x64) @ L0(64x64)
      int u = idx >> 6, c = idx & 63;
      float a = 0.f;
#pragma unroll 8
      for (int m = 0; m < 64; m++) a += W2[u * 64 + m] * L0[m * 64 + c];
      Wf[idx] = sA * a;
    } else if (idx < 4096) {                // WB: W1(64x32) @ L1(32x32)
      int t = idx - 2048;
      int u = t >> 5, c = t & 31;
      float a = 0.f;
#pragma unroll 8
      for (int m = 0; m < 32; m++) a += W1[u * 32 + m] * L1[m * 32 + c];
      Wf[idx] = sB * a;
    } else if (idx < 4608) {                // WC: W4(16x32) @ L1(32x32)
      int t = idx - 4096;
      int u = t >> 5, c = t & 31;
      float a = 0.f;
#pragma unroll 8
      for (int m = 0; m < 32; m++) a += W4[u * 32 + m] * L1[m * 32 + c];
      Wf[idx] = sC * a;
    } else {                                // WD: W3(32x16) @ L2(16x16)
      int t = idx - 4608;
      int u = t >> 4, c = t & 15;
      float a = 0.f;
#pragma unroll 8
      for (int m = 0; m < 16; m++) a += W3[u * 16 + m] * L2[m * 16 + c];
      Wf[idx] = sD * a;
    }
    return;
  }

  // -------- fused kNN block
  __shared__ float4 cnd[3072];                        // 48 KB raw coord image
  __shared__ float pd[NSUB][QPB][9];                  // 36.9 KB
  __shared__ unsigned short pi[NSUB][QPB][9];         // 18.4 KB
  __shared__ float thrS[QPB];

  const int blk = blockIdx.x;
  const int b = blk >> 6;
  const int chunk = blk & 63;
  const int qi  = threadIdx.x & 63;           // query lane
  const int sub = threadIdx.x >> 6;           // 0..15
  const int iq  = chunk * 64 + qi;
  const float* cb = coords + (size_t)b * NN * 3;
  const float4* cb4 = (const float4*)cb;

  {  // A1: stage all 4096 candidates: 3072 float4, 3 per thread, coalesced
    int t = threadIdx.x;
    cnd[t]        = cb4[t];
    cnd[1024 + t] = cb4[1024 + t];
    cnd[2048 + t] = cb4[2048 + t];
  }
  const float qx = cb[iq * 3 + 0], qy = cb[iq * 3 + 1], qz = cb[iq * 3 + 2];
  __syncthreads();

  const int j0 = sub * 256;

  // ---- A2: top-2 distances over [j0, j0+256) (no self mask; see A3)
  float t0v = 3.0e38f, t1v = 3.0e38f;
#pragma unroll 8
  for (int g = 0; g < 64; ++g) {
    int f = 3 * (sub * 64 + g);
    float4 f0 = cnd[f + 0];                   // wave-uniform -> broadcast
    float4 f1 = cnd[f + 1];
    float4 f2 = cnd[f + 2];
    float xs[4] = {f0.x, f0.w, f1.z, f2.y};
    float ys[4] = {f0.y, f1.x, f1.w, f2.z};
    float zs[4] = {f0.z, f1.y, f2.x, f2.w};
#pragma unroll
    for (int c = 0; c < 4; ++c) {
      float dx = xs[c] - qx, dy = ys[c] - qy, dz = zs[c] - qz;
      float d2 = dx * dx + dy * dy + dz * dz;
      t1v = __builtin_amdgcn_fmed3f(t0v, t1v, d2);
      t0v = fminf(t0v, d2);
    }
  }
  pd[sub][qi][0] = t0v;
  pd[sub][qi][1] = t1v;
  __syncthreads();

  // ---- A3: thr = 9th smallest of 32 values (self-0 present exactly once)
  if (threadIdx.x < 64) {
    const int q = threadIdx.x;
    float md[9];
#pragma unroll
    for (int k = 0; k < 9; k++) md[k] = 3.0e38f;
    for (int s = 0; s < NSUB; s++) {
      insD9(pd[s][q][0], md);
      insD9(pd[s][q][1], md);
    }
    thrS[q] = md[8];
  }
  __syncthreads();

  // ---- A4: group-guarded exact collect (self masked here)
  const float tq = thrS[qi];
  float bd[KNBR];
  int bi[KNBR];
#pragma unroll
  for (int k = 0; k < KNBR; k++) { bd[k] = 3.0e38f; bi[k] = 0; }
#pragma unroll 2
  for (int g = 0; g < 64; ++g) {
    int base = j0 + 4 * g;
    int f = 3 * (sub * 64 + g);
    float4 f0 = cnd[f + 0];
    float4 f1 = cnd[f + 1];
    float4 f2 = cnd[f + 2];
    float xs[4] = {f0.x, f0.w, f1.z, f2.y};
    float ys[4] = {f0.y, f1.x, f1.w, f2.z};
    float zs[4] = {f0.z, f1.y, f2.x, f2.w};
    float d2s[4];
#pragma unroll
    for (int c = 0; c < 4; ++c) {
      float dx = xs[c] - qx, dy = ys[c] - qy, dz = zs[c] - qz;
      float d2 = dx * dx + dy * dy + dz * dz;
      d2s[c] = (base + c == iq) ? 3.0e38f : d2;
    }
    float m4 = fminf(fminf(d2s[0], d2s[1]), fminf(d2s[2], d2s[3]));
    if (m4 <= tq) {                           // rare
#pragma unroll
      for (int c = 0; c < 4; ++c)
        if (d2s[c] <= tq) insertDI(d2s[c], base + c, bd, bi);
    }
  }
#pragma unroll
  for (int k = 0; k < KNBR; k++) {
    pd[sub][qi][k] = bd[k];
    pi[sub][qi][k] = (unsigned short)bi[k];
  }
  __syncthreads();

  // ---- A5: final merge (ascending sub = ascending j) -> nbr (global ids)
  if (threadIdx.x < 64) {
    const int q = threadIdx.x;
    float md[KNBR];
    int mi[KNBR];
#pragma unroll
    for (int k = 0; k < KNBR; k++) { md[k] = 3.0e38f; mi[k] = 0; }
    for (int s = 0; s < NSUB; s++) {
#pragma unroll
      for (int k = 0; k < KNBR; k++) {
        float vd = pd[s][q][k];
        if (vd < md[KNBR - 1]) insertDI(vd, (int)pi[s][q][k], md, mi);
      }
    }
    int* nr = nbr + (size_t)(b * NN + chunk * 64 + q) * KNBR;
#pragma unroll
    for (int k = 0; k < KNBR; k++) nr[k] = b * NN + mi[k];  // global node id
  }
}

// ---- msg prefetch chunk: 4 neighbor rows in registers. Arrays indexed only
// ---- by constant unrolled indices (rule #20). Two instances issued BEFORE
// ---- any consume -> one latency exposure per node instead of two. Fits the
// ---- honored (256,4) cap of 128 VGPR (~116 est); tripwire = WRITE_SIZE.
#define CH_DECL(P)                                                  \
  const float* P##fr[4];                                            \
  float P##xv[4], P##av0[4], P##av1[4], P##av2[4],                  \
        P##bv0[4], P##bv1[4], P##bv2[4], P##bv3[4], P##bv4[4];

#define CH_LOAD(P, H)                                               \
  do {                                                              \
    _Pragma("unroll") for (int i = 0; i < 4; i++) {                 \
      P##fr[i] = feats + (size_t)snbw[4 * (H) + i] * DF;            \
      P##xv[i] = P##fr[i][u];                                       \
    }                                                               \
    if (u < 32) {                                                   \
      _Pragma("unroll") for (int i = 0; i < 4; i++) {               \
        P##av0[i] = P##fr[i][64 + 3 * u];                           \
        P##av1[i] = P##fr[i][65 + 3 * u];                           \
        P##av2[i] = P##fr[i][66 + 3 * u];                           \
      }                                                             \
      if (u < 16) {                                                 \
        _Pragma("unroll") for (int i = 0; i < 4; i++) {             \
          P##bv0[i] = P##fr[i][160 + 5 * u];                        \
          P##bv1[i] = P##fr[i][161 + 5 * u];                        \
          P##bv2[i] = P##fr[i][162 + 5 * u];                        \
          P##bv3[i] = P##fr[i][163 + 5 * u];                        \
          P##bv4[i] = P##fr[i][164 + 5 * u];                        \
        }                                                           \
      }                                                             \
    }                                                               \
  } while (0)

#define CH_CONS(P, H)                                               \
  do {                                                              \
    _Pragma("unroll") for (int i = 0; i < 4; i++) {                 \
      const int e = 4 * (H) + i;                                    \
      float X = sevw[e * 3 + 0];                                    \
      float Y = sevw[e * 3 + 1];                                    \
      float Z = sevw[e * 3 + 2];                                    \
      float sxv = S_ * X, syv = S_ * Y, szv = S_ * Z;               \
      float txv = T_ * X, tyv = T_ * Y, t2z = 2.f * T_ * Z;         \
      z0x += P##xv[i] * X;                                          \
      z0y += P##xv[i] * Y;                                          \
      z0z += P##xv[i] * Z;                                          \
      if (u < 32) {                                                 \
        s1 += P##av0[i] * X + P##av1[i] * Y + P##av2[i] * Z;        \
        p0 += P##av0[i] * syv + P##av1[i] * sxv;                    \
        p1 += P##av0[i] * szv + P##av2[i] * sxv;                    \
        p2 += P##av1[i] * szv + P##av2[i] * syv;                    \
        p3 += P##av0[i] * sxv - P##av1[i] * syv;                    \
        p4 += P##av2[i] * t2z - P##av0[i] * txv - P##av1[i] * tyv;  \
        if (u < 16) {                                               \
          q0 += P##bv0[i] * syv + P##bv1[i] * szv +                 \
                P##bv3[i] * sxv - P##bv4[i] * txv;                  \
          q1 += P##bv0[i] * sxv + P##bv2[i] * szv -                 \
                P##bv3[i] * syv - P##bv4[i] * tyv;                  \
          q2 += P##bv1[i] * sxv + P##bv2[i] * syv + P##bv4[i] * t2z;\
        }                                                           \
      }                                                             \
    }                                                               \
  } while (0)

// ---------------------------------------------------------------------------
// Kernel 2: gather + moments + fused weights + output.
// One wave per node; 4 nodes/block. (256,4): cap 128 VGPR, HONORED at this
// block size (R4: VGPR 56 spill-free) — unlike 1024-thr kernels (pinned 64).
// Chunked XCD swizzle (proven 22.8 MB FETCH). Epilogue coalesced (R4 form).
//
// Moments per node (432 floats in LDS):
//   S1[32] @0 | Z0[64][3] @32 | P[32][5] @224 | Q[16][3] @384
// ---------------------------------------------------------------------------
__global__ __launch_bounds__(256, 4) void msg_kernel(
    const float* __restrict__ feats, const float* __restrict__ coords,
    const int* __restrict__ nbr, const float* __restrict__ Wf,
    float* __restrict__ out) {
  __shared__ float accb[4][432];
  __shared__ float sev[4][KNBR][3];
  __shared__ int snb[4][KNBR];

  const int bid = ((blockIdx.x & 7) << 9) | (blockIdx.x >> 3);  // XCD chunks
  const int w = threadIdx.x >> 6;   // wave within block -> node slot
  const int u = threadIdx.x & 63;   // lane
  const int node = bid * 4 + w;

  if (u < KNBR) {
    int jg = nbr[(size_t)node * KNBR + u];
    snb[w][u] = jg;
    sev[w][u][0] = coords[(size_t)jg * 3 + 0] - coords[(size_t)node * 3 + 0];
    sev[w][u][1] = coords[(size_t)jg * 3 + 1] - coords[(size_t)node * 3 + 1];
    sev[w][u][2] = coords[(size_t)jg * 3 + 2] - coords[(size_t)node * 3 + 2];
  }
  __syncthreads();

  const float S_ = 0.31622776601683794f;  // 1/sqrt(10)
  const float T_ = 0.18257418583505536f;  // 1/sqrt(30)
  const int* snbw = snb[w];
  const float* sevw = &sev[w][0][0];

  float z0x = 0.f, z0y = 0.f, z0z = 0.f;
  float s1 = 0.f, p0 = 0.f, p1 = 0.f, p2 = 0.f, p3 = 0.f, p4 = 0.f;
  float q0 = 0.f, q1 = 0.f, q2 = 0.f;

  CH_DECL(cA_)
  CH_DECL(cB_)
  CH_LOAD(cA_, 0);                 // issue ALL 8 rows' loads before any
  CH_LOAD(cB_, 1);                 // consumer FMA: one latency wait per node
  CH_CONS(cA_, 0);
  CH_CONS(cB_, 1);

  float* A = accb[w];
  A[32 + 3 * u + 0] = z0x;
  A[32 + 3 * u + 1] = z0y;
  A[32 + 3 * u + 2] = z0z;
  if (u < 32) {
    A[u] = s1;
    float* pp = A + 224 + 5 * u;
    pp[0] = p0; pp[1] = p1; pp[2] = p2; pp[3] = p3; pp[4] = p4;
  }
  if (u < 16) {
    float* qq = A + 384 + 3 * u;
    qq[0] = q0; qq[1] = q1; qq[2] = q2;
  }
  __syncthreads();

  const float* WA = Wf;          // 32x64
  const float* WB = Wf + 2048;   // 64x32
  const float* WC = Wf + 4096;   // 16x32
  const float* WD = Wf + 4608;   // 32x16
  float* orow = out + (size_t)node * DF;

  // y0[u] = sum_m S1[m] * WA[m][u]   (coalesced across lanes)
  {
    float a = 0.f;
#pragma unroll
    for (int m = 0; m < 32; m++) a += A[m] * WA[m * 64 + u];
    orow[u] = a;
  }
  // y1 flat [w1*3+k], 96 outputs (two passes over 64 lanes)
#pragma unroll
  for (int m0 = 0; m0 < 96; m0 += 64) {
    int m = m0 + u;
    if (m < 96) {
      int w1 = m / 3, k = m - w1 * 3;
      float a = 0.f;
#pragma unroll
      for (int t = 0; t < 64; t++) a += A[32 + 3 * t + k] * WB[t * 32 + w1];
#pragma unroll
      for (int t = 0; t < 16; t++) a += A[384 + 3 * t + k] * WC[t * 32 + w1];
      orow[64 + m] = a;
    }
  }
  // y2 flat [w2*5+k], 80 outputs (two passes over 64 lanes)
#pragma unroll
  for (int m0 = 0; m0 < 80; m0 += 64) {
    int m = m0 + u;
    if (m < 80) {
      int w2 = m / 5, k = m - w2 * 5;
      float a = 0.f;
#pragma unroll
      for (int t = 0; t < 32; t++) a += A[224 + 5 * t + k] * WD[t * 16 + w2];
      orow[160 + m] = a;
    }
  }
}

// ---------------------------------------------------------------------------
extern "C" void kernel_launch(void* const* d_in, const int* in_sizes, int n_in,
                              void* d_out, int out_size, void* d_ws,
                              size_t ws_size, hipStream_t stream) {
  const float* feats  = (const float*)d_in[0];
  const float* coords = (const float*)d_in[1];
  const float* W1 = (const float*)d_in[2];
  const float* W2 = (const float*)d_in[3];
  const float* W3 = (const float*)d_in[4];
  const float* W4 = (const float*)d_in[5];
  const float* L0 = (const float*)d_in[6];
  const float* L1 = (const float*)d_in[7];
  const float* L2 = (const float*)d_in[8];
  float* out = (float*)d_out;

  // workspace (floats): Wf[5120] | nbr[131072 ints]  -> ~0.55 MB
  float* Wf  = (float*)d_ws;
  int*   nbr = (int*)((float*)d_ws + 5120);

  knn_all<<<261, 1024, 0, stream>>>(coords, W1, W2, W3, W4, L0, L1, L2, Wf,
                                    nbr);
  msg_kernel<<<4096, 256, 0, stream>>>(feats, coords, nbr, Wf, out);
}